// Round 14
// baseline (186.310 us; speedup 1.0000x reference)
//
#include <hip/hip_runtime.h>
#include <cstddef>

// Critic_43104291783486 — round 14: gload_lds W staging in the r12 high-TLP shell.
// Register-staged weights serialized in r4/r5/r6/r12/r13 (allocator chunks the
// batch; 3.8K cy/step vs 400 cy work). global_load_lds has no registers to
// serialize: 8x 1KB instrs/wave/tile, HW-queued. fp32 LDS [32][260] with
// source-XOR swizzle ((w&1)<<2 chunks) -> scalar B-frag reads are 2-way (free).
// Single W + single X buffer = 37.5KB -> 3 blocks/CU (12 waves); per-step
// exposed gload wait covered by the other 2 blocks. GEMM2 = r12 verbatim.

#define BN 256
#define HD 256
#define FD 64
#define NHD (BN * HD)
#define XS 40    // X/slab row stride (halves)
#define WLS 260  // W1 lds row stride (floats): 1040B, 16B-aligned, bank 4r+c

typedef _Float16 f16x8 __attribute__((ext_vector_type(8)));
typedef _Float16 f16x4 __attribute__((ext_vector_type(4)));
typedef float f32x4 __attribute__((ext_vector_type(4)));

#define GLOAD16(g, l)                                              \
  __builtin_amdgcn_global_load_lds(                                \
      (__attribute__((address_space(1))) void*)(g),                \
      (__attribute__((address_space(3))) void*)(l), 16, 0, 0)

#define BAR_LGKM()                                                         \
  asm volatile("s_waitcnt lgkmcnt(0)" ::: "memory");                       \
  __builtin_amdgcn_s_barrier();                                            \
  asm volatile("" ::: "memory");
#define VMCNT0_BAR()                                                       \
  asm volatile("s_waitcnt vmcnt(0) lgkmcnt(0)" ::: "memory");              \
  __builtin_amdgcn_s_barrier();                                            \
  asm volatile("" ::: "memory");

// ---------- X staging: 64 rows x 32 k fp32 -> regs -> fp16 LDS ----------
__device__ __forceinline__ void x_load(const float* xs0, const float* xs1, int n,
                                       int row0, int kt, int tid, float4 xr[2]) {
  int kOff = kt * 32;
  const float* xs = (kOff < 256) ? xs0 : xs1;   // A-branch: obs then act
  int row = tid >> 2, c = (tid & 3) * 4;
  const float* p = xs + (size_t)(row0 + row) * NHD + n * HD + (kOff & 255) + c;
  xr[0] = *(const float4*)p;
  xr[1] = *(const float4*)(p + 16);
}
__device__ __forceinline__ void x_write(_Float16* Xl, int tid, const float4 xr[2]) {
  int row = tid >> 2, c = (tid & 3) * 4;
  f16x4 a, b;
  a[0] = (_Float16)xr[0].x; a[1] = (_Float16)xr[0].y;
  a[2] = (_Float16)xr[0].z; a[3] = (_Float16)xr[0].w;
  b[0] = (_Float16)xr[1].x; b[1] = (_Float16)xr[1].y;
  b[2] = (_Float16)xr[1].z; b[3] = (_Float16)xr[1].w;
  *(f16x4*)(Xl + row * XS + c) = a;
  *(f16x4*)(Xl + row * XS + c + 16) = b;
}

// ---------- W1 tile gload: [32][WLS] fp32, 1 instr per 256-float row ----------
// Wave w stages rows w*8..w*8+7. Source XOR-swizzled by chunk key (w&1)<<2:
// LDS chunk l holds W chunk l^K4 -> reader XORs col by ((lq&1)<<4) floats.
__device__ __forceinline__ void w_gload(const float* __restrict__ Wg, float* Wl,
                                        int kt, int w, int l) {
  int xoff = (l ^ ((w & 1) << 2)) << 2;    // swizzled float offset within row
#pragma unroll
  for (int s = 0; s < 8; ++s) {
    int row = w * 8 + s;
    GLOAD16(Wg + (size_t)(kt * 32 + row) * HD + xoff, Wl + (size_t)row * WLS);
  }
}

// ---------- W2 half stage (r12 verbatim): fp16 [khi=16][64 col][klo=8] ----------
__device__ __forceinline__ void w2_stage(const float* __restrict__ W2g, _Float16* Wl,
                                         int half, int w, int l) {
#pragma unroll
  for (int cg = 0; cg < 4; ++cg) {
    int khi = w * 4 + cg;
    const float* p = W2g + (size_t)(half * 128 + khi * 8) * FD + l;
    f16x8 v;
#pragma unroll
    for (int r = 0; r < 8; ++r) v[r] = (_Float16)p[(size_t)r * FD];
    *(f16x8*)(Wl + ((size_t)(khi * 64 + l)) * 8) = v;
  }
}

// ---------- GEMM1 compute: one 32-k step, 16 MFMA/wave ----------
// A-frag: b128 from Xl (row m*16+lrow, k lq*8..+7) — r3-r13 verified.
// B-frag: 8 scalar fp32 reads (conflict-free 2-way via swizzle) + cvt.
__device__ __forceinline__ void g1_compute(const float* Wl, const _Float16* Xl,
                                           int lrow, int lq, const int wcol[4],
                                           f32x4 acc[4][4]) {
  const float* wbase = Wl + (size_t)(lq * 8) * WLS;
  f16x8 b[4];
#pragma unroll
  for (int nf = 0; nf < 4; ++nf) {
    const float* p = wbase + wcol[nf];
    f16x8 t;
#pragma unroll
    for (int j = 0; j < 8; ++j) t[j] = (_Float16)p[(size_t)j * WLS];
    b[nf] = t;
  }
#pragma unroll
  for (int m = 0; m < 4; ++m) {
    f16x8 a = *(const f16x8*)(Xl + (m * 16 + lrow) * XS + lq * 8);
#pragma unroll
    for (int nf = 0; nf < 4; ++nf)
      acc[m][nf] = __builtin_amdgcn_mfma_f32_16x16x32_f16(a, b[nf], acc[m][nf], 0, 0, 0);
  }
}

// C1(64x256) = X(64xK) @ W1(Kx256), K = NK*32.
template <int NK>
__device__ __forceinline__ void run_gemm1(const float* xs0, const float* xs1,
                                          const float* __restrict__ Wg,
                                          int n, int row0, int tid, int lrow, int lq,
                                          const int wcol[4], int w, int l,
                                          float* Wl, _Float16* Xl,
                                          f32x4 acc[4][4]) {
  float4 xr[2];
  // prologue: X(0) regs + W(0) gloads; one exposed latency
  x_load(xs0, xs1, n, row0, 0, tid, xr);
  w_gload(Wg, Wl, 0, w, l);
  x_write(Xl, tid, xr);                  // waits xr only (older than gloads)
  VMCNT0_BAR();                          // W(0)+X(0) resident & published
#pragma unroll 1
  for (int kt = 0; kt < NK; ++kt) {
    if (kt + 1 < NK) x_load(xs0, xs1, n, row0, kt + 1, tid, xr);  // hides under compute
    g1_compute(Wl, Xl, lrow, lq, wcol, acc);
    BAR_LGKM();                          // all waves done reading W[kt],X[kt]
    if (kt + 1 < NK) {
      w_gload(Wg, Wl, kt + 1, w, l);     // HW-queued, zero VGPR
      x_write(Xl, tid, xr);              // waits xr only (gloads younger)
      VMCNT0_BAR();                      // tile kt+1 resident & published
    }
  }
  BAR_LGKM();                            // close reads before gemm2 overwrites Wl
}

// ---------- GEMM2: C2(64x64) += relu(C1+b1) @ W2, 8 x 32-k slab bounces ----------
__device__ __forceinline__ void gemm2_branch(const f32x4 acc[4][4], f32x4 acc2[4],
                                             const float* __restrict__ W2g,
                                             const float* __restrict__ b1g,
                                             _Float16* Wl, _Float16* slab,
                                             int lrow, int lq, int Nbase, int w, int l) {
  float bv[4];
#pragma unroll
  for (int nf = 0; nf < 4; ++nf) bv[nf] = b1g[Nbase + nf * 16 + lrow];  // L2-hot
  w2_stage(W2g, Wl, 0, w, l);
#pragma unroll
  for (int s = 0; s < 8; ++s) {
    if (w == (s >> 1)) {
#pragma unroll
      for (int m = 0; m < 4; ++m)
#pragma unroll
        for (int nf2 = 0; nf2 < 2; ++nf2) {
          const int nf = (s & 1) * 2 + nf2;  // static
#pragma unroll
          for (int r = 0; r < 4; ++r)
            slab[(m * 16 + lq * 4 + r) * XS + nf2 * 16 + lrow] =
                (_Float16)fmaxf(acc[m][nf][r] + bv[nf], 0.f);
        }
    }
    BAR_LGKM();                          // slab (+W2 writes) published
    f16x8 a2 = *(const f16x8*)(slab + (w * 16 + lrow) * XS + lq * 8);
    f16x8 bb[4];
#pragma unroll
    for (int nf = 0; nf < 4; ++nf)
      bb[nf] = *(const f16x8*)(Wl + ((size_t)(((s & 3) * 4 + lq) * 64 + nf * 16 + lrow)) * 8);
#pragma unroll
    for (int nf = 0; nf < 4; ++nf)
      acc2[nf] = __builtin_amdgcn_mfma_f32_16x16x32_f16(a2, bb[nf], acc2[nf], 0, 0, 0);
    BAR_LGKM();                          // reads done before next writer/stage
    if (s == 3) w2_stage(W2g, Wl, 1, w, l);
  }
}

__global__ __launch_bounds__(256, 3) void phase1_kernel(
    const float* __restrict__ obs, const float* __restrict__ act,
    const float* __restrict__ V_W1, const float* __restrict__ V_b1,
    const float* __restrict__ V_W2, const float* __restrict__ V_b2,
    const float* __restrict__ A_W1, const float* __restrict__ A_b1,
    const float* __restrict__ A_W2, const float* __restrict__ A_b2,
    float* __restrict__ Q) {
  __shared__ __align__(16) float Wbuf[32 * WLS];   // 32.5KB: W1 fp32 / W2 fp16 [16][64][8]
  __shared__ __align__(16) _Float16 Xl[2560];      // 5KB: X [64][40] / h slab
  // 37.5KB total -> 3 blocks/CU (LDS would allow 4; VGPR tier gives 3)

  int tid = threadIdx.x;
  int l = tid & 63, w = tid >> 6;
  int lrow = l & 15, lq = l >> 4;
  int Nbase = w * 64;
  int wcol[4];
#pragma unroll
  for (int nf = 0; nf < 4; ++nf)
    wcol[nf] = (Nbase + nf * 16 + lrow) ^ ((lq & 1) << 4);   // read-side swizzle
  int bid = blockIdx.x;
  int n = bid & 255;                   // node; quarters share an XCD residue
  int row0 = (bid >> 8) * 64;          // batch quarter

  f32x4 acc[4][4];
  f32x4 acc2[4];
#pragma unroll
  for (int j = 0; j < 4; ++j) acc2[j] = (f32x4){0.f, 0.f, 0.f, 0.f};

  // ---------------- V branch (NK=8) ----------------
#pragma unroll
  for (int m = 0; m < 4; ++m)
#pragma unroll
    for (int nf = 0; nf < 4; ++nf) acc[m][nf] = (f32x4){0.f, 0.f, 0.f, 0.f};
  run_gemm1<8>(obs, obs, V_W1 + (size_t)n * HD * HD, n, row0, tid, lrow, lq,
               wcol, w, l, Wbuf, Xl, acc);
  gemm2_branch(acc, acc2, V_W2 + (size_t)n * HD * FD, V_b1 + n * HD,
               (_Float16*)Wbuf, Xl, lrow, lq, Nbase, w, l);

  // ---------------- A branch (NK=16) ----------------
#pragma unroll
  for (int m = 0; m < 4; ++m)
#pragma unroll
    for (int nf = 0; nf < 4; ++nf) acc[m][nf] = (f32x4){0.f, 0.f, 0.f, 0.f};
  run_gemm1<16>(obs, act, A_W1 + (size_t)n * 2 * HD * HD, n, row0, tid, lrow, lq,
                wcol, w, l, Wbuf, Xl, acc);
  gemm2_branch(acc, acc2, A_W2 + (size_t)n * HD * FD, A_b1 + n * HD,
               (_Float16*)Wbuf, Xl, lrow, lq, Nbase, w, l);

  // ---------------- Q = acc2 + V_b2 + A_b2 ----------------
  const float* vb2 = V_b2 + n * FD;
  const float* ab2 = A_b2 + n * FD;
#pragma unroll
  for (int nf = 0; nf < 4; ++nf) {
    int f = nf * 16 + lrow;
    float bias = vb2[f] + ab2[f];
#pragma unroll
    for (int rr = 0; rr < 4; ++rr) {
      int row = row0 + w * 16 + lq * 4 + rr;
      Q[(size_t)row * (BN * FD) + n * FD + f] = acc2[nf][rr] + bias;
    }
  }
}

// ---------------- phase 2: gather + subset-min + chi + mean ----------------
__global__ __launch_bounds__(256) void phase2_kernel(const float* __restrict__ Q,
                                                     const float* __restrict__ chi_m,
                                                     const int* __restrict__ le,
                                                     float* __restrict__ out) {
  int b = blockIdx.x;
  int n = threadIdx.x;
  // int64-vs-int32 layout hedge: centers = arange(N) => int32 layout has le[5]==1.
  int step = (le[5] == 1) ? 1 : 2;
  const int* e = le + n * 5 * step;
  int c  = e[0 * step] & (BN - 1);
  int n0 = e[1 * step] & (BN - 1);
  int n1 = e[2 * step] & (BN - 1);
  int n2 = e[3 * step] & (BN - 1);
  int n3 = e[4 * step] & (BN - 1);
  const float* ch = chi_m + n * 45;   // (HEADS=3, S=15)
  float cm[15];
#pragma unroll
  for (int s = 0; s < 15; ++s) cm[s] = (ch[s] + ch[15 + s] + ch[30 + s]) * (1.f / 3.f);
  const float* qb = Q + (size_t)b * (BN * FD);
  const float* q0 = qb + n0 * FD;
  const float* q1 = qb + n1 * FD;
  const float* q2 = qb + n2 * FD;
  const float* q3 = qb + n3 * FD;
  const float* qc = qb + c * FD;
  float acc = 0.f;
#pragma unroll
  for (int f = 0; f < FD; f += 4) {
    float4 v0 = *(const float4*)(q0 + f);
    float4 v1 = *(const float4*)(q1 + f);
    float4 v2 = *(const float4*)(q2 + f);
    float4 v3 = *(const float4*)(q3 + f);
    float4 vc = *(const float4*)(qc + f);
    const float* p0 = (const float*)&v0;
    const float* p1 = (const float*)&v1;
    const float* p2 = (const float*)&v2;
    const float* p3 = (const float*)&v3;
    const float* pc = (const float*)&vc;
#pragma unroll
    for (int u = 0; u < 4; ++u) {
      float a = p0[u], bq = p1[u], cq = p2[u], d = p3[u];
      float m01 = fminf(a, bq), m02 = fminf(a, cq), m03 = fminf(a, d);
      float m12 = fminf(bq, cq), m13 = fminf(bq, d), m23 = fminf(cq, d);
      float m012 = fminf(m01, cq), m013 = fminf(m01, d);
      float m023 = fminf(m02, d),  m123 = fminf(m12, d);
      float m0123 = fminf(m01, m23);
      float chi = cm[0] * a   + cm[1] * bq   + cm[2] * m01  + cm[3] * cq
                + cm[4] * m02 + cm[5] * m12  + cm[6] * m012 + cm[7] * d
                + cm[8] * m03 + cm[9] * m13  + cm[10] * m013 + cm[11] * m23
                + cm[12] * m023 + cm[13] * m123 + cm[14] * m0123;
      acc += chi + pc[u];
    }
  }
  out[b * BN + n] = acc * (1.f / 64.f);
}

extern "C" void kernel_launch(void* const* d_in, const int* in_sizes, int n_in,
                              void* d_out, int out_size, void* d_ws, size_t ws_size,
                              hipStream_t stream) {
  (void)in_sizes; (void)n_in; (void)out_size; (void)ws_size;
  const float* obs  = (const float*)d_in[0];
  const float* act  = (const float*)d_in[1];
  const float* V_W1 = (const float*)d_in[2];
  const float* V_b1 = (const float*)d_in[3];
  const float* V_W2 = (const float*)d_in[4];
  const float* V_b2 = (const float*)d_in[5];
  const float* A_W1 = (const float*)d_in[6];
  const float* A_b1 = (const float*)d_in[7];
  const float* A_W2 = (const float*)d_in[8];
  const float* A_b2 = (const float*)d_in[9];
  const float* chim = (const float*)d_in[10];
  const int*   le   = (const int*)d_in[11];
  float* Q   = (float*)d_ws;            // 16 MB scratch: Q[B][N][F]
  float* out = (float*)d_out;

  phase1_kernel<<<dim3(1024), dim3(256), 0, stream>>>(obs, act, V_W1, V_b1, V_W2, V_b2,
                                                      A_W1, A_b1, A_W2, A_b2, Q);
  phase2_kernel<<<dim3(256), dim3(256), 0, stream>>>(Q, chim, le, out);
}

// Round 15
// 126.821 us; speedup vs baseline: 1.4691x; 1.4691x over previous
//
#include <hip/hip_runtime.h>
#include <cstddef>

// Critic_43104291783486 — round 15: direct global->register W B-fragments with
// a LEGAL register budget. Root cause closed in r12/r14: acc AGPRs share the
// unified file, so (256,4)+acc64 left 64 arch VGPRs (r12) and (256,2)+acc128
// left 128 (r5) — W reg-batches were always squeezed into serialization.
// Here: 64x256 tile (acc[4][4] = 64 AGPR) + launch_bounds(256,2) -> 192 arch
// VGPRs for ~110 needed. W never touches LDS: no W barriers (per-wave vmcnt
// pacing), no fp32 scalar LDS reads. LDS = 21KB (X tile + W2/slab for GEMM2).
// Grid: node's 4 quarters 8 bids apart -> same XCD, same round (W L2 dedupe).

#define BN 256
#define HD 256
#define FD 64
#define NHD (BN * HD)
#define XS 40    // X/slab row stride (halves)

typedef _Float16 f16x8 __attribute__((ext_vector_type(8)));
typedef _Float16 f16x4 __attribute__((ext_vector_type(4)));
typedef float f32x4 __attribute__((ext_vector_type(4)));

#define BAR_LGKM()                                                         \
  asm volatile("s_waitcnt lgkmcnt(0)" ::: "memory");                       \
  __builtin_amdgcn_s_barrier();                                            \
  asm volatile("" ::: "memory");

__device__ __forceinline__ f16x8 pack8(const float v[8]) {
  f16x8 r;
#pragma unroll
  for (int i = 0; i < 8; ++i) r[i] = (_Float16)v[i];
  return r;
}

// ---------- X staging: 64 rows x 32 k fp32 -> regs -> fp16 LDS ----------
__device__ __forceinline__ void x_load(const float* xs0, const float* xs1, int n,
                                       int row0, int kt, int tid, float4 xr[2]) {
  int kOff = kt * 32;
  const float* xs = (kOff < 256) ? xs0 : xs1;   // A-branch: obs then act
  int row = tid >> 2, c = (tid & 3) * 4;
  const float* p = xs + (size_t)(row0 + row) * NHD + n * HD + (kOff & 255) + c;
  xr[0] = *(const float4*)p;
  xr[1] = *(const float4*)(p + 16);
}
__device__ __forceinline__ void x_write(_Float16* Xl, int tid, const float4 xr[2]) {
  int row = tid >> 2, c = (tid & 3) * 4;
  f16x4 a, b;
  a[0] = (_Float16)xr[0].x; a[1] = (_Float16)xr[0].y;
  a[2] = (_Float16)xr[0].z; a[3] = (_Float16)xr[0].w;
  b[0] = (_Float16)xr[1].x; b[1] = (_Float16)xr[1].y;
  b[2] = (_Float16)xr[1].z; b[3] = (_Float16)xr[1].w;
  *(f16x4*)(Xl + row * XS + c) = a;
  *(f16x4*)(Xl + row * XS + c + 16) = b;
}

// ---------- W1 B-fragment batch: 4 frags x 8 dwords, per-lane global ----------
// B-frag elem j (lane l): W[kt*32 + (l>>4)*8 + j][Nbase + nf*16 + (l&15)].
// Per instr: 4 x 64B segments (16-lane groups contiguous). L2-served for 3 of
// 4 quarter-blocks (same XCD). 32 regs/batch; two named batches (depth-2).
__device__ __forceinline__ void w1_load(const float* __restrict__ wb, float wf[4][8]) {
#pragma unroll
  for (int nf = 0; nf < 4; ++nf)
#pragma unroll
    for (int j = 0; j < 8; ++j) wf[nf][j] = wb[(size_t)j * HD + nf * 16];
}

// ---------- GEMM1 compute: 4 b128 A reads + 16 MFMA ----------
__device__ __forceinline__ void g1_compute(const f16x8 b[4], const _Float16* Xl,
                                           int lrow, int lq, f32x4 acc[4][4]) {
#pragma unroll
  for (int m = 0; m < 4; ++m) {
    f16x8 a = *(const f16x8*)(Xl + (m * 16 + lrow) * XS + lq * 8);
#pragma unroll
    for (int nf = 0; nf < 4; ++nf)
      acc[m][nf] = __builtin_amdgcn_mfma_f32_16x16x32_f16(a, b[nf], acc[m][nf], 0, 0, 0);
  }
}

// One K-step. WFC: the batch holding W[kt] (reloaded with W[kt+2] after cvt).
#define G1_STEP(KT, WFC)                                                     \
  {                                                                          \
    const int kt_ = (KT);                                                    \
    BAR_LGKM()                      /* X[kt] published by all waves */       \
    f16x8 bfr[4];                   /* waits W[kt] (issued at kt-2: ~0) */   \
    _Pragma("unroll") for (int nf = 0; nf < 4; ++nf) bfr[nf] = pack8(WFC[nf]); \
    if (kt_ + 2 < NK) w1_load(wb + (size_t)(kt_ + 2) * 32 * HD, WFC);        \
    if (kt_ + 1 < NK) x_load(xs0, xs1, n, row0, kt_ + 1, tid, xr);           \
    g1_compute(bfr, Xl, lrow, lq, acc);                                      \
    BAR_LGKM()                      /* all waves done reading X[kt] */       \
    if (kt_ + 1 < NK) x_write(Xl, tid, xr);  /* waits only xr batch */       \
  }

// C1(64x256) = X(64xK) @ W1(Kx256), K = NK*32 (NK even).
template <int NK>
__device__ __forceinline__ void run_gemm1(const float* xs0, const float* xs1,
                                          const float* __restrict__ Wg,
                                          int n, int row0, int tid, int lrow, int lq,
                                          int Nbase, _Float16* Xl, f32x4 acc[4][4]) {
  const float* wb = Wg + (size_t)(lq * 8) * HD + Nbase + lrow;
  float wfA[4][8], wfB[4][8];
  float4 xr[2];
  w1_load(wb, wfA);                             // W[0]
  w1_load(wb + (size_t)32 * HD, wfB);           // W[1]
  x_load(xs0, xs1, n, row0, 0, tid, xr);
  x_write(Xl, tid, xr);                         // waits xr only (W stays in flight)
#pragma unroll 1
  for (int kt = 0; kt < NK; kt += 2) {
    G1_STEP(kt, wfA)
    G1_STEP(kt + 1, wfB)
  }
  BAR_LGKM()                                    // close Xl reads before slab reuse
}

// ---------- W2 half stage (r12 pattern): fp16 [khi=16][64 col][klo=8] ----------
__device__ __forceinline__ void w2_stage(const float* __restrict__ W2g, _Float16* Wl,
                                         int half, int w, int l) {
#pragma unroll
  for (int cg = 0; cg < 4; ++cg) {
    int khi = w * 4 + cg;
    const float* p = W2g + (size_t)(half * 128 + khi * 8) * FD + l;
    f16x8 v;
#pragma unroll
    for (int r = 0; r < 8; ++r) v[r] = (_Float16)p[(size_t)r * FD];
    *(f16x8*)(Wl + ((size_t)(khi * 64 + l)) * 8) = v;
  }
}

// ---------- GEMM2: C2(64x64) += relu(C1+b1) @ W2, 8 x 32-k slab bounces ----------
__device__ __forceinline__ void gemm2_branch(const f32x4 acc[4][4], f32x4 acc2[4],
                                             const float* __restrict__ W2g,
                                             const float* __restrict__ b1g,
                                             _Float16* Wl, _Float16* slab,
                                             int lrow, int lq, int Nbase, int w, int l) {
  float bv[4];
#pragma unroll
  for (int nf = 0; nf < 4; ++nf) bv[nf] = b1g[Nbase + nf * 16 + lrow];  // L2-hot
  w2_stage(W2g, Wl, 0, w, l);
#pragma unroll
  for (int s = 0; s < 8; ++s) {
    if (w == (s >> 1)) {
#pragma unroll
      for (int m = 0; m < 4; ++m)
#pragma unroll
        for (int nf2 = 0; nf2 < 2; ++nf2) {
          const int nf = (s & 1) * 2 + nf2;  // static
#pragma unroll
          for (int r = 0; r < 4; ++r)
            slab[(m * 16 + lq * 4 + r) * XS + nf2 * 16 + lrow] =
                (_Float16)fmaxf(acc[m][nf][r] + bv[nf], 0.f);
        }
    }
    BAR_LGKM();                          // slab (+W2 writes) published
    f16x8 a2 = *(const f16x8*)(slab + (w * 16 + lrow) * XS + lq * 8);
    f16x8 bb[4];
#pragma unroll
    for (int nf = 0; nf < 4; ++nf)
      bb[nf] = *(const f16x8*)(Wl + ((size_t)(((s & 3) * 4 + lq) * 64 + nf * 16 + lrow)) * 8);
#pragma unroll
    for (int nf = 0; nf < 4; ++nf)
      acc2[nf] = __builtin_amdgcn_mfma_f32_16x16x32_f16(a2, bb[nf], acc2[nf], 0, 0, 0);
    BAR_LGKM();                          // reads done before next writer/stage
    if (s == 3) w2_stage(W2g, Wl, 1, w, l);
  }
}

__global__ __launch_bounds__(256, 2) void phase1_kernel(
    const float* __restrict__ obs, const float* __restrict__ act,
    const float* __restrict__ V_W1, const float* __restrict__ V_b1,
    const float* __restrict__ V_W2, const float* __restrict__ V_b2,
    const float* __restrict__ A_W1, const float* __restrict__ A_b1,
    const float* __restrict__ A_W2, const float* __restrict__ A_b2,
    float* __restrict__ Q) {
  __shared__ __align__(16) _Float16 Wl[8192];   // 16KB: W2 [16][64][8] (GEMM2 only)
  __shared__ __align__(16) _Float16 Xl[2560];   // 5KB: X [64][40] / h slab

  int tid = threadIdx.x;
  int l = tid & 63, w = tid >> 6;
  int lrow = l & 15, lq = l >> 4;
  int Nbase = w * 64;                  // wave owns 64 C1-cols
  int bid = blockIdx.x;
  // node's 4 quarters at bids {n%8 + 8q + 32*(n/8)}: same XCD (stride 8) and
  // same dispatch round (within 32 consecutive bids) -> W1 L2 dedupe.
  int n = ((bid >> 5) << 3) | (bid & 7);
  int row0 = ((bid >> 3) & 3) * 64;    // batch quarter

  f32x4 acc[4][4];
  f32x4 acc2[4];
#pragma unroll
  for (int j = 0; j < 4; ++j) acc2[j] = (f32x4){0.f, 0.f, 0.f, 0.f};

  // ---------------- V branch (NK=8) ----------------
#pragma unroll
  for (int m = 0; m < 4; ++m)
#pragma unroll
    for (int nf = 0; nf < 4; ++nf) acc[m][nf] = (f32x4){0.f, 0.f, 0.f, 0.f};
  {
    const int NK = 8;
    const float* xs0 = obs; const float* xs1 = obs;
    const float* Wg = V_W1 + (size_t)n * HD * HD;
    run_gemm1<8>(xs0, xs1, Wg, n, row0, tid, lrow, lq, Nbase, Xl, acc);
  }
  gemm2_branch(acc, acc2, V_W2 + (size_t)n * HD * FD, V_b1 + n * HD,
               Wl, Xl, lrow, lq, Nbase, w, l);

  // ---------------- A branch (NK=16) ----------------
#pragma unroll
  for (int m = 0; m < 4; ++m)
#pragma unroll
    for (int nf = 0; nf < 4; ++nf) acc[m][nf] = (f32x4){0.f, 0.f, 0.f, 0.f};
  {
    const float* xs0 = obs; const float* xs1 = act;
    const float* Wg = A_W1 + (size_t)n * 2 * HD * HD;
    run_gemm1<16>(xs0, xs1, Wg, n, row0, tid, lrow, lq, Nbase, Xl, acc);
  }
  gemm2_branch(acc, acc2, A_W2 + (size_t)n * HD * FD, A_b1 + n * HD,
               Wl, Xl, lrow, lq, Nbase, w, l);

  // ---------------- Q = acc2 + V_b2 + A_b2 ----------------
  const float* vb2 = V_b2 + n * FD;
  const float* ab2 = A_b2 + n * FD;
#pragma unroll
  for (int nf = 0; nf < 4; ++nf) {
    int f = nf * 16 + lrow;
    float bias = vb2[f] + ab2[f];
#pragma unroll
    for (int rr = 0; rr < 4; ++rr) {
      int row = row0 + w * 16 + lq * 4 + rr;
      Q[(size_t)row * (BN * FD) + n * FD + f] = acc2[nf][rr] + bias;
    }
  }
}

// ---------------- phase 2: gather + subset-min + chi + mean ----------------
__global__ __launch_bounds__(256) void phase2_kernel(const float* __restrict__ Q,
                                                     const float* __restrict__ chi_m,
                                                     const int* __restrict__ le,
                                                     float* __restrict__ out) {
  int b = blockIdx.x;
  int n = threadIdx.x;
  // int64-vs-int32 layout hedge: centers = arange(N) => int32 layout has le[5]==1.
  int step = (le[5] == 1) ? 1 : 2;
  const int* e = le + n * 5 * step;
  int c  = e[0 * step] & (BN - 1);
  int n0 = e[1 * step] & (BN - 1);
  int n1 = e[2 * step] & (BN - 1);
  int n2 = e[3 * step] & (BN - 1);
  int n3 = e[4 * step] & (BN - 1);
  const float* ch = chi_m + n * 45;   // (HEADS=3, S=15)
  float cm[15];
#pragma unroll
  for (int s = 0; s < 15; ++s) cm[s] = (ch[s] + ch[15 + s] + ch[30 + s]) * (1.f / 3.f);
  const float* qb = Q + (size_t)b * (BN * FD);
  const float* q0 = qb + n0 * FD;
  const float* q1 = qb + n1 * FD;
  const float* q2 = qb + n2 * FD;
  const float* q3 = qb + n3 * FD;
  const float* qc = qb + c * FD;
  float acc = 0.f;
#pragma unroll
  for (int f = 0; f < FD; f += 4) {
    float4 v0 = *(const float4*)(q0 + f);
    float4 v1 = *(const float4*)(q1 + f);
    float4 v2 = *(const float4*)(q2 + f);
    float4 v3 = *(const float4*)(q3 + f);
    float4 vc = *(const float4*)(qc + f);
    const float* p0 = (const float*)&v0;
    const float* p1 = (const float*)&v1;
    const float* p2 = (const float*)&v2;
    const float* p3 = (const float*)&v3;
    const float* pc = (const float*)&vc;
#pragma unroll
    for (int u = 0; u < 4; ++u) {
      float a = p0[u], bq = p1[u], cq = p2[u], d = p3[u];
      float m01 = fminf(a, bq), m02 = fminf(a, cq), m03 = fminf(a, d);
      float m12 = fminf(bq, cq), m13 = fminf(bq, d), m23 = fminf(cq, d);
      float m012 = fminf(m01, cq), m013 = fminf(m01, d);
      float m023 = fminf(m02, d),  m123 = fminf(m12, d);
      float m0123 = fminf(m01, m23);
      float chi = cm[0] * a   + cm[1] * bq   + cm[2] * m01  + cm[3] * cq
                + cm[4] * m02 + cm[5] * m12  + cm[6] * m012 + cm[7] * d
                + cm[8] * m03 + cm[9] * m13  + cm[10] * m013 + cm[11] * m23
                + cm[12] * m023 + cm[13] * m123 + cm[14] * m0123;
      acc += chi + pc[u];
    }
  }
  out[b * BN + n] = acc * (1.f / 64.f);
}

extern "C" void kernel_launch(void* const* d_in, const int* in_sizes, int n_in,
                              void* d_out, int out_size, void* d_ws, size_t ws_size,
                              hipStream_t stream) {
  (void)in_sizes; (void)n_in; (void)out_size; (void)ws_size;
  const float* obs  = (const float*)d_in[0];
  const float* act  = (const float*)d_in[1];
  const float* V_W1 = (const float*)d_in[2];
  const float* V_b1 = (const float*)d_in[3];
  const float* V_W2 = (const float*)d_in[4];
  const float* V_b2 = (const float*)d_in[5];
  const float* A_W1 = (const float*)d_in[6];
  const float* A_b1 = (const float*)d_in[7];
  const float* A_W2 = (const float*)d_in[8];
  const float* A_b2 = (const float*)d_in[9];
  const float* chim = (const float*)d_in[10];
  const int*   le   = (const int*)d_in[11];
  float* Q   = (float*)d_ws;            // 16 MB scratch: Q[B][N][F]
  float* out = (float*)d_out;

  phase1_kernel<<<dim3(1024), dim3(256), 0, stream>>>(obs, act, V_W1, V_b1, V_W2, V_b2,
                                                      A_W1, A_b1, A_W2, A_b2, Q);
  phase2_kernel<<<dim3(256), dim3(256), 0, stream>>>(Q, chim, le, out);
}